// Round 12
// baseline (20.881 us; speedup 1.0000x reference)
//
#include <hip/hip_runtime.h>
#include <math.h>

#define BB 2048   // batch B
#define NN 512    // classes N
#define DD 256    // dim D

typedef __attribute__((ext_vector_type(8))) _Float16 f16x8;  // 8 f16 (4 VGPRs)
typedef __attribute__((ext_vector_type(4))) float f32x4;

#define MFMA_F16 __builtin_amdgcn_mfma_f32_16x16x32_f16

__device__ __forceinline__ ushort f2h(float f) {             // RNE f32->f16
    union { _Float16 h; ushort u; } c; c.h = (_Float16)f; return c.u;
}
// pack 4 scaled floats into 4 f16 (one uint2)
__device__ __forceinline__ uint2 pack4h(f32x4 v, float s) {
    uint2 r;
    r.x = (unsigned)f2h(v.x * s) | ((unsigned)f2h(v.y * s) << 16);
    r.y = (unsigned)f2h(v.z * s) | ((unsigned)f2h(v.w * s) << 16);
    return r;
}
// stable fast asinh: sign(z) * log(|z| + sqrt(z^2+1))
__device__ __forceinline__ float fast_asinh(float z) {
    float az = fabsf(z);
    float r = __logf(az + sqrtf(fmaf(az, az, 1.0f)));
    return copysignf(r, z);
}

// ---------------- K1: one WAVE per row (R11 structure, f16 single) --------
// Waves [0,BB): x -> Poincare ball, f16 PRE-SWIZZLED (el ^= (row&7)<<3 per
// 64-elem chunk) for K2's global_load_lds+swizzled-ds_read path.
// Waves [BB,BB+NN): p,a -> p_poincare / a_poincare, PLAIN f16 (K2 loads these
// per-lane into VGPRs) + per-row scalars.
__global__ __launch_bounds__(256) void hmlr_transform(
    const float* __restrict__ x, const float* __restrict__ a_vals,
    const float* __restrict__ p_vals,
    ushort* __restrict__ Xf, ushort* __restrict__ Pf, ushort* __restrict__ Af,
    float* __restrict__ y2, float* __restrict__ p2s, float* __restrict__ pas,
    float* __restrict__ ans, float* __restrict__ ks)
{
    const int lane = threadIdx.x & 63;
    const int wid  = blockIdx.x * 4 + (threadIdx.x >> 6);   // row id, < BB+NN
    const int e0   = lane * 4;                              // 4 elems per lane

    if (wid < BB) {
        const int r = wid;
        f32x4 v = *(const f32x4*)&x[(size_t)r * DD + e0];
        float ss = v.x * v.x + v.y * v.y + v.z * v.z + v.w * v.w;
        #pragma unroll
        for (int m = 32; m; m >>= 1) ss += __shfl_xor(ss, m, 64);
        float norm0 = sqrtf(ss);
        float fac = fminf(1.0f, 1.0f / (norm0 + 1e-5f));    // CLIP_R = 1
        float u = fmaxf(norm0 * fac, 1e-5f);
        float th = tanhf(u);                                 // sqrt_c = 1
        float en = fmaxf(th, 1e-5f);
        float wgt = (en > 0.999f) ? (0.999f / en) : 1.0f;    // project
        float s = fac * (th / u) * wgt;                      // x -> xb scale
        if (lane == 0) { float fn = th * wgt; y2[r] = fn * fn; }
        int es = e0 ^ ((r & 7) << 3);                        // pre-swizzle
        *(uint2*)&Xf[(size_t)r * DD + es] = pack4h(v, s);
    } else {
        const int n = wid - BB;
        f32x4 pv = *(const f32x4*)&p_vals[(size_t)n * DD + e0];
        f32x4 av = *(const f32x4*)&a_vals[(size_t)n * DD + e0];
        float sp = pv.x * pv.x + pv.y * pv.y + pv.z * pv.z + pv.w * pv.w;
        float sa = av.x * av.x + av.y * av.y + av.z * av.z + av.w * av.w;
        float sx = pv.x * av.x + pv.y * av.y + pv.z * av.z + pv.w * av.w;
        #pragma unroll
        for (int m = 32; m; m >>= 1) {
            sp += __shfl_xor(sp, m, 64);
            sa += __shfl_xor(sa, m, 64);
            sx += __shfl_xor(sx, m, 64);
        }
        float u = fmaxf(sqrtf(sp), 1e-5f);
        float th = tanhf(u);
        float spp = th / u;                                  // p -> p_poincare
        float p2 = th * th;
        float conf = 1.0f - p2;                              // conformal
        if (lane == 0) {
            p2s[n] = p2;
            pas[n] = spp * conf * sx;                        // P . A
            float an = sqrtf(sa) * conf;                     // ||a_poincare||
            ans[n] = an;
            ks[n] = (2.0f / conf) * an;                      // lam * a_norm
        }
        *(uint2*)&Pf[(size_t)n * DD + e0] = pack4h(pv, spp); // PLAIN layout
        *(uint2*)&Af[(size_t)n * DD + e0] = pack4h(av, conf);
    }
}

// ---------------- K2: 32x64 tile, 512 blocks (2/CU), 1 barrier -----------
// X tile (32 rows, whole K) via global_load_lds into 16 KiB static LDS;
// P/A fragments (full K of one row each) direct global->VGPR (64 regs,
// pinned); 8 x {1 swizzled ds_read_b128 + 2 MFMA}; fused asinh epilogue.
__global__ __launch_bounds__(512, 4) void hmlr_gemm(
    const ushort* __restrict__ Xf, const ushort* __restrict__ Pf,
    const ushort* __restrict__ Af,
    const float* __restrict__ y2, const float* __restrict__ p2s,
    const float* __restrict__ pas, const float* __restrict__ ans,
    const float* __restrict__ ks, float* __restrict__ out)
{
    __shared__ ushort Xs[32][256];         // 16 KiB, swizzled rows

    const int t    = threadIdx.x;
    const int lane = t & 63;
    const int w    = t >> 6;               // wave 0..7
    const int bid  = blockIdx.x;
    // XCD-aware: xcd = bid&7 (round-robin dispatch). The 8 blocks sharing one
    // b-tile (same X rows) all land on the same XCD -> X re-reads are L2 hits.
    const int xcd  = bid & 7;
    const int j    = bid >> 3;             // 0..63
    const int b0   = (xcd * 8 + (j >> 3)) * 32;
    const int n0   = (j & 7) * 64;
    const int wr   = w >> 2;               // b half: 16 rows
    const int wc   = w & 3;                // n strip: 16 cols
    const int ge   = (lane >> 4) * 8;      // elem group within 32-elem k-slice
    const int ram  = wr * 16 + (lane & 15);
    const int rbn  = wc * 16 + (lane & 15);

    // ---- stage X tile: 16 chunks of 1 KiB (2 rows each), 2 per wave ----
    {
        const int c = w * 2;
        const ushort* src = Xf + (size_t)(b0 + c * 2 + (lane >> 5)) * DD + (lane & 31) * 8;
        ushort* dst = &Xs[c * 2][0];
        #pragma unroll
        for (int i = 0; i < 2; ++i) {
            __builtin_amdgcn_global_load_lds(
                (const __attribute__((address_space(1))) unsigned int*)(const void*)(src + i * 2 * DD),
                (__attribute__((address_space(3))) unsigned int*)(void*)(dst + i * 2 * DD),
                16, 0, 0);
        }
    }

    // ---- B fragments (plain layout) direct to VGPRs, full K ----
    const ushort* pr = Pf + (size_t)(n0 + rbn) * DD;
    const ushort* ar = Af + (size_t)(n0 + rbn) * DD;
    f16x8 pf[8], af[8];
    #pragma unroll
    for (int q = 0; q < 8; ++q) {
        pf[q] = *(const f16x8*)(pr + q * 32 + ge);
        af[q] = *(const f16x8*)(ar + q * 32 + ge);
    }

    // ---- epilogue scalars (overlap the staging latency) ----
    const int n = n0 + rbn;
    float p2 = p2s[n], pa = pas[n], an = ans[n], kk = ks[n];
    float yv[4];
    #pragma unroll
    for (int rg = 0; rg < 4; ++rg)
        yv[rg] = y2[b0 + wr * 16 + (lane >> 4) * 4 + rg];

    // pin everything + memory clobber: forbids re-loading inside the loop
    #pragma unroll
    for (int q = 0; q < 8; ++q)
        asm volatile("" :: "v"(pf[q]), "v"(af[q]));
    asm volatile("" :: "v"(p2), "v"(pa), "v"(an), "v"(kk));
    #pragma unroll
    for (int i = 0; i < 4; ++i) asm volatile("" :: "v"(yv[i]));
    asm volatile("" ::: "memory");

    __syncthreads();                       // X tile resident (drains vmcnt)

    // ---- GEMM: 8 x {1 ds_read_b128 + 2 MFMA} ----
    f32x4 axy = {0.f,0.f,0.f,0.f}, axa = {0.f,0.f,0.f,0.f};
    const int swzA = (ram & 7) << 3;
    const ushort* r0 = &Xs[ram][0];
    #pragma unroll
    for (int q = 0; q < 8; ++q) {
        int f = q * 32 + ge;
        int p = (f & ~63) | ((f & 63) ^ swzA);
        f16x8 xf = *(const f16x8*)(r0 + p);
        axy = MFMA_F16(xf, pf[q], axy, 0, 0, 0);
        axa = MFMA_F16(xf, af[q], axa, 0, 0, 0);
    }

    // ---- epilogue: C/D map col=lane&15, row=(lane>>4)*4+reg ----
    #pragma unroll
    for (int rg = 0; rg < 4; ++rg) {
        int b = b0 + wr * 16 + (lane >> 4) * 4 + rg;
        float yy  = yv[rg];
        float xy  = -axy[rg];                        // (-P).X
        float xa  =  axa[rg];
        float dnm = 1.f + 2.f * xy + p2 * yy + 1e-5f;
        float alpha = (1.f + 2.f * xy + yy) / dnm;   // coeff on (-P)
        float beta  = (1.f - p2) / dnm;              // coeff on X
        float num  = 2.f * (beta * xa - alpha * pa);
        float mob2 = alpha * alpha * p2 + beta * beta * yy
                   + 2.f * alpha * beta * xy;
        float den  = an * (1.f - mob2);
        out[(size_t)b * NN + n] = kk * fast_asinh(num / den);
    }
}

extern "C" void kernel_launch(void* const* d_in, const int* in_sizes, int n_in,
                              void* d_out, int out_size, void* d_ws, size_t ws_size,
                              hipStream_t stream) {
    const float* x      = (const float*)d_in[0];
    const float* a_vals = (const float*)d_in[1];
    const float* p_vals = (const float*)d_in[2];
    float* out = (float*)d_out;

    ushort* Xf = (ushort*)d_ws;                 // [BB][DD] f16 (pre-swizzled)
    ushort* Pf = Xf + (size_t)BB * DD;          // [NN][DD] f16 plain
    ushort* Af = Pf + (size_t)NN * DD;
    float*  y2  = (float*)(Af + (size_t)NN * DD);
    float*  p2s = y2 + BB;
    float*  pas = p2s + NN;
    float*  ans = pas + NN;
    float*  ks  = ans + NN;

    hipLaunchKernelGGL(hmlr_transform, dim3((BB + NN) / 4), dim3(256), 0, stream,
                       x, a_vals, p_vals, Xf, Pf, Af, y2, p2s, pas, ans, ks);
    hipLaunchKernelGGL(hmlr_gemm, dim3(512), dim3(512), 0, stream,
                       Xf, Pf, Af, y2, p2s, pas, ans, ks, out);
}

// Round 13
// 16.569 us; speedup vs baseline: 1.2602x; 1.2602x over previous
//
#include <hip/hip_runtime.h>
#include <math.h>

#define BB 2048   // batch B
#define NN 512    // classes N
#define DD 256    // dim D

typedef __attribute__((ext_vector_type(8))) _Float16 f16x8;  // 8 f16 (4 VGPRs)
typedef __attribute__((ext_vector_type(4))) float f32x4;

#define MFMA_F16 __builtin_amdgcn_mfma_f32_16x16x32_f16

__device__ __forceinline__ ushort f2h(float f) {             // RNE f32->f16
    union { _Float16 h; ushort u; } c; c.h = (_Float16)f; return c.u;
}
// pack 4 scaled floats into 4 f16 (one uint2)
__device__ __forceinline__ uint2 pack4h(f32x4 v, float s) {
    uint2 r;
    r.x = (unsigned)f2h(v.x * s) | ((unsigned)f2h(v.y * s) << 16);
    r.y = (unsigned)f2h(v.z * s) | ((unsigned)f2h(v.w * s) << 16);
    return r;
}
// stable fast asinh: sign(z) * log(|z| + sqrt(z^2+1))
__device__ __forceinline__ float fast_asinh(float z) {
    float az = fabsf(z);
    float r = __logf(az + sqrtf(fmaf(az, az, 1.0f)));
    return copysignf(r, z);
}

// ---------------- K1: one WAVE per row (R11 structure, f16 single) --------
// Waves [0,BB): x -> Poincare ball. Waves [BB,BB+NN): p,a -> poincare + scalars.
// ALL matrices written f16 PRE-SWIZZLED (el ^= (row&7)<<3 within each 64-elem
// chunk) -- they all flow through K2's global_load_lds + swizzled ds_read.
__global__ __launch_bounds__(256) void hmlr_transform(
    const float* __restrict__ x, const float* __restrict__ a_vals,
    const float* __restrict__ p_vals,
    ushort* __restrict__ Xf, ushort* __restrict__ Pf, ushort* __restrict__ Af,
    float* __restrict__ y2, float* __restrict__ p2s, float* __restrict__ pas,
    float* __restrict__ ans, float* __restrict__ ks)
{
    const int lane = threadIdx.x & 63;
    const int wid  = blockIdx.x * 4 + (threadIdx.x >> 6);   // row id, < BB+NN
    const int e0   = lane * 4;                              // 4 elems per lane

    if (wid < BB) {
        const int r = wid;
        f32x4 v = *(const f32x4*)&x[(size_t)r * DD + e0];
        float ss = v.x * v.x + v.y * v.y + v.z * v.z + v.w * v.w;
        #pragma unroll
        for (int m = 32; m; m >>= 1) ss += __shfl_xor(ss, m, 64);
        float norm0 = sqrtf(ss);
        float fac = fminf(1.0f, 1.0f / (norm0 + 1e-5f));    // CLIP_R = 1
        float u = fmaxf(norm0 * fac, 1e-5f);
        float th = tanhf(u);                                 // sqrt_c = 1
        float en = fmaxf(th, 1e-5f);
        float wgt = (en > 0.999f) ? (0.999f / en) : 1.0f;    // project
        float s = fac * (th / u) * wgt;                      // x -> xb scale
        if (lane == 0) { float fn = th * wgt; y2[r] = fn * fn; }
        int es = e0 ^ ((r & 7) << 3);                        // pre-swizzle
        *(uint2*)&Xf[(size_t)r * DD + es] = pack4h(v, s);
    } else {
        const int n = wid - BB;
        f32x4 pv = *(const f32x4*)&p_vals[(size_t)n * DD + e0];
        f32x4 av = *(const f32x4*)&a_vals[(size_t)n * DD + e0];
        float sp = pv.x * pv.x + pv.y * pv.y + pv.z * pv.z + pv.w * pv.w;
        float sa = av.x * av.x + av.y * av.y + av.z * av.z + av.w * av.w;
        float sx = pv.x * av.x + pv.y * av.y + pv.z * av.z + pv.w * av.w;
        #pragma unroll
        for (int m = 32; m; m >>= 1) {
            sp += __shfl_xor(sp, m, 64);
            sa += __shfl_xor(sa, m, 64);
            sx += __shfl_xor(sx, m, 64);
        }
        float u = fmaxf(sqrtf(sp), 1e-5f);
        float th = tanhf(u);
        float spp = th / u;                                  // p -> p_poincare
        float p2 = th * th;
        float conf = 1.0f - p2;                              // conformal
        if (lane == 0) {
            p2s[n] = p2;
            pas[n] = spp * conf * sx;                        // P . A
            float an = sqrtf(sa) * conf;                     // ||a_poincare||
            ans[n] = an;
            ks[n] = (2.0f / conf) * an;                      // lam * a_norm
        }
        int es = e0 ^ ((n & 7) << 3);
        *(uint2*)&Pf[(size_t)n * DD + es] = pack4h(pv, spp);
        *(uint2*)&Af[(size_t)n * DD + es] = pack4h(av, conf);
    }
}

// ---------------- K2: 64x64 tile, 8 waves, BK=64 dbuf (R11 core, 3 mats) ----
// Dynamic LDS: [2][3][64][64] ushort = 48 KiB. Per k-slice: 4 ds_read_b128 +
// 6 MFMA. XCD-aware bid mapping; early pinned scalar prefetch; fast asinh.
__global__ __launch_bounds__(512) void hmlr_gemm(
    const ushort* __restrict__ Xf, const ushort* __restrict__ Pf,
    const ushort* __restrict__ Af,
    const float* __restrict__ y2, const float* __restrict__ p2s,
    const float* __restrict__ pas, const float* __restrict__ ans,
    const float* __restrict__ ks, float* __restrict__ out)
{
    extern __shared__ ushort T[];          // [2][3][64][64]

    const int t    = threadIdx.x;
    const int lane = t & 63;
    const int w    = t >> 6;               // wave 0..7
    const int bid  = blockIdx.x;
    // XCD-aware mapping: xcd = bid&7 (dispatch round-robin). All 8 blocks
    // sharing one b0 (same X rows) land on the SAME xcd -> X re-reads L2-hit.
    const int xcd  = bid & 7;
    const int j    = bid >> 3;             // 0..31
    const int b0   = (xcd * 4 + (j >> 3)) * 64;
    const int n0   = (j & 7) * 64;
    const int wr   = w >> 2;               // m half: 32 rows
    const int wc   = w & 3;                // n strip: 16 cols

    const ushort* bases[3] = {Xf, Pf, Af};

    f32x4 axy0 = {0.f,0.f,0.f,0.f}, axy1 = {0.f,0.f,0.f,0.f};
    f32x4 axa0 = {0.f,0.f,0.f,0.f}, axa1 = {0.f,0.f,0.f,0.f};

    // Stage one BK=64 slice of all 3 mats (24 KiB) into buf. 24 wave-chunks
    // of 1 KiB: g = w*3+i -> mat g>>3, 8-row group g&7.
    auto stage = [&](int buf, int s) {
        #pragma unroll
        for (int i = 0; i < 3; ++i) {
            int g = w * 3 + i;
            int mat = g >> 3;
            int sub = g & 7;
            int grow = (mat == 0 ? b0 : n0) + sub * 8 + (lane >> 3);
            const ushort* src = bases[mat] + (size_t)grow * DD + s * 64 + (lane & 7) * 8;
            const ushort* dst = T + (((buf * 3 + mat) * 64 + sub * 8) * 64);
            __builtin_amdgcn_global_load_lds(
                (const __attribute__((address_space(1))) unsigned int*)(const void*)src,
                (__attribute__((address_space(3))) unsigned int*)(void*)dst,
                16, 0, 0);
        }
    };

    const int ram = wr * 32 + (lane & 15);
    const int rbn = wc * 16 + (lane & 15);
    const int gb  = (lane >> 4) << 4;      // 16B group within 128B row

    stage(0, 0);

    // ---- early epilogue-scalar prefetch (overlaps staging/MFMA) ----
    const int n = n0 + rbn;
    float p2 = p2s[n], pa = pas[n], an = ans[n], kk = ks[n];
    float yv[8];
    #pragma unroll
    for (int m = 0; m < 2; ++m)
        #pragma unroll
        for (int rg = 0; rg < 4; ++rg)
            yv[m * 4 + rg] = y2[b0 + wr * 32 + m * 16 + (lane >> 4) * 4 + rg];
    asm volatile("" :: "v"(p2), "v"(pa), "v"(an), "v"(kk));
    #pragma unroll
    for (int i = 0; i < 8; ++i) asm volatile("" :: "v"(yv[i]));

    for (int s = 0; s < 4; ++s) {
        __syncthreads();                   // vmcnt drain: buf[s&1] ready
        if (s < 3) stage((s + 1) & 1, s + 1);
        const int bf = s & 1;
        #pragma unroll
        for (int ksl = 0; ksl < 2; ++ksl) {
            const int kb = ksl * 64 + gb;
            const ushort* base = T + (bf * 3 * 64 * 64);
            const char* x0 = (const char*)(base + (0 * 64 + ram) * 64);
            const int sa0 = kb ^ ((ram & 7) << 4);
            const int sb0 = kb ^ ((rbn & 7) << 4);
            const int sa1 = kb ^ (((ram + 16) & 7) << 4);   // == sa0
            f16x8 xf0 = *(const f16x8*)(x0 + sa0);
            f16x8 xf1 = *(const f16x8*)(x0 + 16 * 128 + sa1);
            f16x8 pf  = *(const f16x8*)((const char*)(base + (1 * 64 + rbn) * 64) + sb0);
            f16x8 af  = *(const f16x8*)((const char*)(base + (2 * 64 + rbn) * 64) + sb0);
            axy0 = MFMA_F16(xf0, pf, axy0, 0, 0, 0);
            axy1 = MFMA_F16(xf1, pf, axy1, 0, 0, 0);
            axa0 = MFMA_F16(xf0, af, axa0, 0, 0, 0);
            axa1 = MFMA_F16(xf1, af, axa1, 0, 0, 0);
        }
    }

    // Epilogue. C/D map: col = lane&15, row = (lane>>4)*4 + reg.
    #pragma unroll
    for (int m = 0; m < 2; ++m) {
        f32x4 acc_xy = m ? axy1 : axy0;
        f32x4 acc_xa = m ? axa1 : axa0;
        #pragma unroll
        for (int rg = 0; rg < 4; ++rg) {
            int b = b0 + wr * 32 + m * 16 + (lane >> 4) * 4 + rg;
            float yy  = yv[m * 4 + rg];
            float xy  = -acc_xy[rg];                     // (-P).X
            float xa  =  acc_xa[rg];
            float dnm = 1.f + 2.f * xy + p2 * yy + 1e-5f;
            float alpha = (1.f + 2.f * xy + yy) / dnm;   // coeff on (-P)
            float beta  = (1.f - p2) / dnm;              // coeff on X
            float num  = 2.f * (beta * xa - alpha * pa);
            float mob2 = alpha * alpha * p2 + beta * beta * yy
                       + 2.f * alpha * beta * xy;
            float den  = an * (1.f - mob2);
            out[(size_t)b * NN + n] = kk * fast_asinh(num / den);
        }
    }
}

extern "C" void kernel_launch(void* const* d_in, const int* in_sizes, int n_in,
                              void* d_out, int out_size, void* d_ws, size_t ws_size,
                              hipStream_t stream) {
    const float* x      = (const float*)d_in[0];
    const float* a_vals = (const float*)d_in[1];
    const float* p_vals = (const float*)d_in[2];
    float* out = (float*)d_out;

    ushort* Xf = (ushort*)d_ws;                 // [BB][DD] f16 (pre-swizzled)
    ushort* Pf = Xf + (size_t)BB * DD;          // [NN][DD] f16 (pre-swizzled)
    ushort* Af = Pf + (size_t)NN * DD;
    float*  y2  = (float*)(Af + (size_t)NN * DD);
    float*  p2s = y2 + BB;
    float*  pas = p2s + NN;
    float*  ans = pas + NN;
    float*  ks  = ans + NN;

    (void)hipFuncSetAttribute(reinterpret_cast<const void*>(hmlr_gemm),
                              hipFuncAttributeMaxDynamicSharedMemorySize, 49152);

    hipLaunchKernelGGL(hmlr_transform, dim3((BB + NN) / 4), dim3(256), 0, stream,
                       x, a_vals, p_vals, Xf, Pf, Af, y2, p2s, pas, ans, ks);
    hipLaunchKernelGGL(hmlr_gemm, dim3(256), dim3(512), 49152, stream,
                       Xf, Pf, Af, y2, p2s, pas, ans, ks, out);
}

// Round 14
// 16.240 us; speedup vs baseline: 1.2858x; 1.0203x over previous
//
#include <hip/hip_runtime.h>
#include <math.h>

#define BB 2048   // batch B
#define NN 512    // classes N
#define DD 256    // dim D

typedef __attribute__((ext_vector_type(8))) _Float16 f16x8;  // 8 f16 (4 VGPRs)
typedef __attribute__((ext_vector_type(4))) float f32x4;

#define MFMA_F16 __builtin_amdgcn_mfma_f32_16x16x32_f16

__device__ __forceinline__ ushort f2h(float f) {             // RNE f32->f16
    union { _Float16 h; ushort u; } c; c.h = (_Float16)f; return c.u;
}
// pack 4 scaled floats into 4 f16 (one uint2)
__device__ __forceinline__ uint2 pack4h(f32x4 v, float s) {
    uint2 r;
    r.x = (unsigned)f2h(v.x * s) | ((unsigned)f2h(v.y * s) << 16);
    r.y = (unsigned)f2h(v.z * s) | ((unsigned)f2h(v.w * s) << 16);
    return r;
}
// stable fast asinh: sign(z) * log(|z| + sqrt(z^2+1))
__device__ __forceinline__ float fast_asinh(float z) {
    float az = fabsf(z);
    float r = __logf(az + sqrtf(fmaf(az, az, 1.0f)));
    return copysignf(r, z);
}

// ---------------- K1: one WAVE per row (unchanged from R13) ----------------
// Waves [0,BB): x -> Poincare ball. Waves [BB,BB+NN): p,a -> poincare + scalars.
// All matrices f16, PRE-SWIZZLED: el ^= (row&7)<<3 within each 64-elem chunk.
__global__ __launch_bounds__(256) void hmlr_transform(
    const float* __restrict__ x, const float* __restrict__ a_vals,
    const float* __restrict__ p_vals,
    ushort* __restrict__ Xf, ushort* __restrict__ Pf, ushort* __restrict__ Af,
    float* __restrict__ y2, float* __restrict__ p2s, float* __restrict__ pas,
    float* __restrict__ ans, float* __restrict__ ks)
{
    const int lane = threadIdx.x & 63;
    const int wid  = blockIdx.x * 4 + (threadIdx.x >> 6);   // row id, < BB+NN
    const int e0   = lane * 4;                              // 4 elems per lane

    if (wid < BB) {
        const int r = wid;
        f32x4 v = *(const f32x4*)&x[(size_t)r * DD + e0];
        float ss = v.x * v.x + v.y * v.y + v.z * v.z + v.w * v.w;
        #pragma unroll
        for (int m = 32; m; m >>= 1) ss += __shfl_xor(ss, m, 64);
        float norm0 = sqrtf(ss);
        float fac = fminf(1.0f, 1.0f / (norm0 + 1e-5f));    // CLIP_R = 1
        float u = fmaxf(norm0 * fac, 1e-5f);
        float th = tanhf(u);                                 // sqrt_c = 1
        float en = fmaxf(th, 1e-5f);
        float wgt = (en > 0.999f) ? (0.999f / en) : 1.0f;    // project
        float s = fac * (th / u) * wgt;                      // x -> xb scale
        if (lane == 0) { float fn = th * wgt; y2[r] = fn * fn; }
        int es = e0 ^ ((r & 7) << 3);                        // pre-swizzle
        *(uint2*)&Xf[(size_t)r * DD + es] = pack4h(v, s);
    } else {
        const int n = wid - BB;
        f32x4 pv = *(const f32x4*)&p_vals[(size_t)n * DD + e0];
        f32x4 av = *(const f32x4*)&a_vals[(size_t)n * DD + e0];
        float sp = pv.x * pv.x + pv.y * pv.y + pv.z * pv.z + pv.w * pv.w;
        float sa = av.x * av.x + av.y * av.y + av.z * av.z + av.w * av.w;
        float sx = pv.x * av.x + pv.y * av.y + pv.z * av.z + pv.w * av.w;
        #pragma unroll
        for (int m = 32; m; m >>= 1) {
            sp += __shfl_xor(sp, m, 64);
            sa += __shfl_xor(sa, m, 64);
            sx += __shfl_xor(sx, m, 64);
        }
        float u = fmaxf(sqrtf(sp), 1e-5f);
        float th = tanhf(u);
        float spp = th / u;                                  // p -> p_poincare
        float p2 = th * th;
        float conf = 1.0f - p2;                              // conformal
        if (lane == 0) {
            p2s[n] = p2;
            pas[n] = spp * conf * sx;                        // P . A
            float an = sqrtf(sa) * conf;                     // ||a_poincare||
            ans[n] = an;
            ks[n] = (2.0f / conf) * an;                      // lam * a_norm
        }
        int es = e0 ^ ((n & 7) << 3);
        *(uint2*)&Pf[(size_t)n * DD + es] = pack4h(pv, spp);
        *(uint2*)&Af[(size_t)n * DD + es] = pack4h(av, conf);
    }
}

// ---------------- K2: 64x64 tile, whole-K single-stage, ONE barrier ---------
// Dynamic LDS: [3][64][256] ushort = 96 KiB (X, P, A full-K tiles).
// 12 global_load_lds per wave issued at once -> one vmcnt drain -> 8 straight
// k-slices x {4 swizzled ds_read_b128 + 4 MFMA} -> fused asinh epilogue.
__global__ __launch_bounds__(512) void hmlr_gemm(
    const ushort* __restrict__ Xf, const ushort* __restrict__ Pf,
    const ushort* __restrict__ Af,
    const float* __restrict__ y2, const float* __restrict__ p2s,
    const float* __restrict__ pas, const float* __restrict__ ans,
    const float* __restrict__ ks, float* __restrict__ out)
{
    extern __shared__ ushort T[];          // [3][64][256]

    const int t    = threadIdx.x;
    const int lane = t & 63;
    const int w    = t >> 6;               // wave 0..7
    const int bid  = blockIdx.x;
    // XCD-aware mapping: xcd = bid&7 (dispatch round-robin). All 8 blocks
    // sharing one b0 (same X rows) land on the SAME xcd -> X re-reads L2-hit.
    const int xcd  = bid & 7;
    const int j    = bid >> 3;             // 0..31
    const int b0   = (xcd * 4 + (j >> 3)) * 64;
    const int n0   = (j & 7) * 64;
    const int wr   = w >> 2;               // m half: 32 rows
    const int wc   = w & 3;                // n strip: 16 cols

    const ushort* bases[3] = {Xf, Pf, Af};

    // ---- stage ALL of X/P/A (whole K) into LDS: 96 chunks of 1 KiB ----
    // chunk g = w*12+i: mat = g>>5, pair c = g&31 (rows c*2, c*2+1).
    // Wave-uniform LDS dst; HW adds lane*16B (lanes 0-31 row c*2, 32-63 row
    // c*2+1). Global source is pre-swizzled so linear copy lands swizzled.
    #pragma unroll
    for (int i = 0; i < 12; ++i) {
        int g = w * 12 + i;
        int mat = g >> 5;
        int c = g & 31;
        int grow = (mat == 0 ? b0 : n0) + c * 2 + (lane >> 5);
        const ushort* src = bases[mat] + (size_t)grow * DD + (lane & 31) * 8;
        const ushort* dst = T + ((mat * 64 + c * 2) * 256);
        __builtin_amdgcn_global_load_lds(
            (const __attribute__((address_space(1))) unsigned int*)(const void*)src,
            (__attribute__((address_space(3))) unsigned int*)(void*)dst,
            16, 0, 0);
    }

    const int ram = wr * 32 + (lane & 15);
    const int rbn = wc * 16 + (lane & 15);
    const int ge  = (lane >> 4) * 8;       // elem group within 32-elem k-slice

    // ---- early epilogue-scalar prefetch (overlaps staging) ----
    const int n = n0 + rbn;
    float p2 = p2s[n], pa = pas[n], an = ans[n], kk = ks[n];
    float yv[8];
    #pragma unroll
    for (int m = 0; m < 2; ++m)
        #pragma unroll
        for (int rg = 0; rg < 4; ++rg)
            yv[m * 4 + rg] = y2[b0 + wr * 32 + m * 16 + (lane >> 4) * 4 + rg];
    asm volatile("" :: "v"(p2), "v"(pa), "v"(an), "v"(kk));
    #pragma unroll
    for (int i = 0; i < 8; ++i) asm volatile("" :: "v"(yv[i]));

    __syncthreads();                       // single drain: everything resident

    // ---- GEMM: 8 x {4 swizzled ds_read_b128 + 4 MFMA}, barrier-free ----
    f32x4 axy0 = {0.f,0.f,0.f,0.f}, axy1 = {0.f,0.f,0.f,0.f};
    f32x4 axa0 = {0.f,0.f,0.f,0.f}, axa1 = {0.f,0.f,0.f,0.f};
    const int swzA = (ram & 7) << 3;       // same for ram+16
    const int swzB = (rbn & 7) << 3;
    const ushort* x0r = T + (size_t)ram * 256;
    const ushort* x1r = T + (size_t)(ram + 16) * 256;
    const ushort* pr  = T + (size_t)(64 + rbn) * 256;
    const ushort* ar  = T + (size_t)(128 + rbn) * 256;

    #pragma unroll
    for (int q = 0; q < 8; ++q) {
        int f = q * 32 + ge;
        int pA = f ^ swzA;                 // XOR stays within 64-elem chunk
        int pB = f ^ swzB;
        f16x8 xf0 = *(const f16x8*)(x0r + pA);
        f16x8 xf1 = *(const f16x8*)(x1r + pA);
        f16x8 pf  = *(const f16x8*)(pr + pB);
        f16x8 af  = *(const f16x8*)(ar + pB);
        axy0 = MFMA_F16(xf0, pf, axy0, 0, 0, 0);
        axy1 = MFMA_F16(xf1, pf, axy1, 0, 0, 0);
        axa0 = MFMA_F16(xf0, af, axa0, 0, 0, 0);
        axa1 = MFMA_F16(xf1, af, axa1, 0, 0, 0);
    }

    // Epilogue. C/D map: col = lane&15, row = (lane>>4)*4 + reg.
    #pragma unroll
    for (int m = 0; m < 2; ++m) {
        f32x4 acc_xy = m ? axy1 : axy0;
        f32x4 acc_xa = m ? axa1 : axa0;
        #pragma unroll
        for (int rg = 0; rg < 4; ++rg) {
            int b = b0 + wr * 32 + m * 16 + (lane >> 4) * 4 + rg;
            float yy  = yv[m * 4 + rg];
            float xy  = -acc_xy[rg];                     // (-P).X
            float xa  =  acc_xa[rg];
            float dnm = 1.f + 2.f * xy + p2 * yy + 1e-5f;
            float alpha = (1.f + 2.f * xy + yy) / dnm;   // coeff on (-P)
            float beta  = (1.f - p2) / dnm;              // coeff on X
            float num  = 2.f * (beta * xa - alpha * pa);
            float mob2 = alpha * alpha * p2 + beta * beta * yy
                       + 2.f * alpha * beta * xy;
            float den  = an * (1.f - mob2);
            out[(size_t)b * NN + n] = kk * fast_asinh(num / den);
        }
    }
}

extern "C" void kernel_launch(void* const* d_in, const int* in_sizes, int n_in,
                              void* d_out, int out_size, void* d_ws, size_t ws_size,
                              hipStream_t stream) {
    const float* x      = (const float*)d_in[0];
    const float* a_vals = (const float*)d_in[1];
    const float* p_vals = (const float*)d_in[2];
    float* out = (float*)d_out;

    ushort* Xf = (ushort*)d_ws;                 // [BB][DD] f16 (pre-swizzled)
    ushort* Pf = Xf + (size_t)BB * DD;          // [NN][DD] f16 (pre-swizzled)
    ushort* Af = Pf + (size_t)NN * DD;
    float*  y2  = (float*)(Af + (size_t)NN * DD);
    float*  p2s = y2 + BB;
    float*  pas = p2s + NN;
    float*  ans = pas + NN;
    float*  ks  = ans + NN;

    (void)hipFuncSetAttribute(reinterpret_cast<const void*>(hmlr_gemm),
                              hipFuncAttributeMaxDynamicSharedMemorySize, 98304);

    hipLaunchKernelGGL(hmlr_transform, dim3((BB + NN) / 4), dim3(256), 0, stream,
                       x, a_vals, p_vals, Xf, Pf, Af, y2, p2s, pas, ans, ks);
    hipLaunchKernelGGL(hmlr_gemm, dim3(256), dim3(512), 98304, stream,
                       Xf, Pf, Af, y2, p2s, pas, ans, ks, out);
}